// Round 4
// baseline (703.181 us; speedup 1.0000x reference)
//
#include <hip/hip_runtime.h>
#include <stdint.h>

#define N_ROWS 12288
#define GSZ (128 * 12288)  // elements per G matrix (bf16)
#define NPART_OFF (9437184 / 4)          // float offset of node partials in ws
#define EPART_OFF ((9437184 + 6291456) / 4)

typedef __attribute__((ext_vector_type(8))) short bf16x8;
typedef __attribute__((ext_vector_type(4))) float f32x4;

union frag_u { bf16x8 v; uint32_t u[4]; };

__device__ __forceinline__ uint32_t f2bf(float x) {
  union { float f; uint32_t u; } c; c.f = x;
  return (c.u + 0x7FFFu + ((c.u >> 16) & 1u)) >> 16;
}
__device__ __forceinline__ uint32_t pk_bf(float a, float b) {
  return f2bf(a) | (f2bf(b) << 16);
}
__device__ __forceinline__ uint32_t pk_pos(float a, float b) {
  return (a > 0.f ? 0x3F80u : 0u) | (b > 0.f ? 0x3F800000u : 0u);
}
__device__ __forceinline__ uint32_t pk_neg(float a, float b) {
  return (a < 0.f ? 0x3F80u : 0u) | (b < 0.f ? 0x3F800000u : 0u);
}

// ---------------------------------------------------------------------------
// Kernel 1: G_j = feats @ W_j  (fp32), stored bf16 TRANSPOSED:
//   gt[j][n][k] = (feats @ W_j)[k][n]
// ---------------------------------------------------------------------------
__global__ __launch_bounds__(256) void gw_kernel(
    const float* __restrict__ feats, const float* __restrict__ node_w,
    const float* __restrict__ edge_w, uint16_t* __restrict__ gt) {
  __shared__ float lf[16 * 128];
  const int t = threadIdx.x;
  const int kb = blockIdx.x * 16;
  {
    const float4* src = (const float4*)(feats + (size_t)kb * 128);
    float4* dst = (float4*)lf;
    dst[t] = src[t];
    dst[t + 256] = src[t + 256];
  }
  __syncthreads();
  const int n = t & 127;
  const int rh = t >> 7;
  const float* wb[3] = {node_w, node_w + 128 * 128, edge_w};
#pragma unroll
  for (int j = 0; j < 3; ++j) {
    const float* W = wb[j] + n;
    float acc[8];
#pragma unroll
    for (int q = 0; q < 8; ++q) acc[q] = 0.f;
    for (int i = 0; i < 128; i += 4) {
      const float w0 = W[(i + 0) * 128];
      const float w1 = W[(i + 1) * 128];
      const float w2 = W[(i + 2) * 128];
      const float w3 = W[(i + 3) * 128];
#pragma unroll
      for (int q = 0; q < 8; ++q) {
        const float4 f = *(const float4*)&lf[(rh * 8 + q) * 128 + i];
        acc[q] = fmaf(f.w, w3, fmaf(f.z, w2, fmaf(f.y, w1, fmaf(f.x, w0, acc[q]))));
      }
    }
    uint4 o;
    o.x = pk_bf(acc[0], acc[1]);
    o.y = pk_bf(acc[2], acc[3]);
    o.z = pk_bf(acc[4], acc[5]);
    o.w = pk_bf(acc[6], acc[7]);
    *(uint4*)(gt + (size_t)j * GSZ + (size_t)n * N_ROWS + kb + rh * 8) = o;
  }
}

// ---------------------------------------------------------------------------
// Kernel 2: barrier-free, LDS-free. 1536 single-wave blocks (= 6 waves/CU).
// Wave tile: 32 rows (mf=2) x 128 cols (nf=8), K-slice 3072 (96 steps of 32).
// A-fragments loaded DIRECTLY from global adjacency (lane l&15 -> row,
// lane>>4 -> k-granule, 8 contiguous f32 = two float4) and VALU-packed to
// {pos,neg,edge} bf16 fragments in registers. B direct from L2-resident gt.
// XCD-affinity: slice=(bid>>1)&3 so XCD pair {2s,2s+1} only touches slice s.
// ---------------------------------------------------------------------------
__global__ __launch_bounds__(64, 2) void fgc_main(
    const float* __restrict__ node_adj, const float* __restrict__ edge_adj,
    const uint16_t* __restrict__ gt, float* __restrict__ node_part,
    float* __restrict__ edge_part) {
  const int l = threadIdx.x & 63;
  const int bid = blockIdx.x;
  const int slice = (bid >> 1) & 3;
  const int rowt = ((bid >> 3) << 1) | (bid & 1);  // 0..383
  const int row0 = rowt * 32;
  const size_t k0 = (size_t)slice * 3072;

  const int r15 = l & 15;
  const int gq = l >> 4;  // k-granule 0..3

  const float* nA = node_adj + (size_t)(row0 + r15) * N_ROWS + k0 + gq * 8;
  const float* nB = nA + (size_t)16 * N_ROWS;
  const float* eA = edge_adj + (size_t)(row0 + r15) * N_ROWS + k0 + gq * 8;
  const float* eB = eA + (size_t)16 * N_ROWS;
  const uint16_t* gBase = gt + (size_t)r15 * N_ROWS + k0 + gq * 8;

  f32x4 accn[2][8], acce[2][8];
#pragma unroll
  for (int a = 0; a < 2; ++a)
#pragma unroll
    for (int b = 0; b < 8; ++b) {
      accn[a][b] = {0.f, 0.f, 0.f, 0.f};
      acce[a][b] = {0.f, 0.f, 0.f, 0.f};
    }

  float4 a0, a1, b0, b1, c0, c1, d0, d1;
  a0 = *(const float4*)(nA);
  a1 = *(const float4*)(nA + 4);
  b0 = *(const float4*)(nB);
  b1 = *(const float4*)(nB + 4);
  c0 = *(const float4*)(eA);
  c1 = *(const float4*)(eA + 4);
  d0 = *(const float4*)(eB);
  d1 = *(const float4*)(eB + 4);

#pragma unroll 1
  for (int st = 0; st < 96; ++st) {
    // pack current batch into bf16 fragments (implicit vmcnt wait here)
    frag_u pA, pB, qA, qB, fA, fB;
    pA.u[0] = pk_pos(a0.x, a0.y); pA.u[1] = pk_pos(a0.z, a0.w);
    pA.u[2] = pk_pos(a1.x, a1.y); pA.u[3] = pk_pos(a1.z, a1.w);
    qA.u[0] = pk_neg(a0.x, a0.y); qA.u[1] = pk_neg(a0.z, a0.w);
    qA.u[2] = pk_neg(a1.x, a1.y); qA.u[3] = pk_neg(a1.z, a1.w);
    pB.u[0] = pk_pos(b0.x, b0.y); pB.u[1] = pk_pos(b0.z, b0.w);
    pB.u[2] = pk_pos(b1.x, b1.y); pB.u[3] = pk_pos(b1.z, b1.w);
    qB.u[0] = pk_neg(b0.x, b0.y); qB.u[1] = pk_neg(b0.z, b0.w);
    qB.u[2] = pk_neg(b1.x, b1.y); qB.u[3] = pk_neg(b1.z, b1.w);
    fA.u[0] = pk_bf(c0.x, c0.y);  fA.u[1] = pk_bf(c0.z, c0.w);
    fA.u[2] = pk_bf(c1.x, c1.y);  fA.u[3] = pk_bf(c1.z, c1.w);
    fB.u[0] = pk_bf(d0.x, d0.y);  fB.u[1] = pk_bf(d0.z, d0.w);
    fB.u[2] = pk_bf(d1.x, d1.y);  fB.u[3] = pk_bf(d1.z, d1.w);

    // issue next adjacency batch immediately (keeps HBM fed through the
    // B-load/MFMA section; no barriers anywhere to drain it)
    if (st < 95) {
      const int ko = (st + 1) * 32;
      a0 = *(const float4*)(nA + ko);
      a1 = *(const float4*)(nA + ko + 4);
      b0 = *(const float4*)(nB + ko);
      b1 = *(const float4*)(nB + ko + 4);
      c0 = *(const float4*)(eA + ko);
      c1 = *(const float4*)(eA + ko + 4);
      d0 = *(const float4*)(eB + ko);
      d1 = *(const float4*)(eB + ko + 4);
    }

    const uint16_t* g0 = gBase + st * 32;
#pragma unroll
    for (int nf = 0; nf < 8; ++nf) {
      const uint16_t* gp = g0 + (size_t)nf * 16 * N_ROWS;
      const bf16x8 v1 = *(const bf16x8*)(gp);
      const bf16x8 v2 = *(const bf16x8*)(gp + GSZ);
      const bf16x8 v3 = *(const bf16x8*)(gp + 2 * GSZ);
      accn[0][nf] = __builtin_amdgcn_mfma_f32_16x16x32_bf16(pA.v, v1, accn[0][nf], 0, 0, 0);
      accn[1][nf] = __builtin_amdgcn_mfma_f32_16x16x32_bf16(pB.v, v1, accn[1][nf], 0, 0, 0);
      accn[0][nf] = __builtin_amdgcn_mfma_f32_16x16x32_bf16(qA.v, v2, accn[0][nf], 0, 0, 0);
      accn[1][nf] = __builtin_amdgcn_mfma_f32_16x16x32_bf16(qB.v, v2, accn[1][nf], 0, 0, 0);
      acce[0][nf] = __builtin_amdgcn_mfma_f32_16x16x32_bf16(fA.v, v3, acce[0][nf], 0, 0, 0);
      acce[1][nf] = __builtin_amdgcn_mfma_f32_16x16x32_bf16(fB.v, v3, acce[1][nf], 0, 0, 0);
    }
  }

  // accumulate partials: C/D frag row=(lane>>4)*4+q, col=lane&15
#pragma unroll
  for (int nf = 0; nf < 8; ++nf) {
    const int col = nf * 16 + r15;
#pragma unroll
    for (int mf = 0; mf < 2; ++mf) {
      const f32x4 nv = accn[mf][nf];
      const f32x4 ev = acce[mf][nf];
#pragma unroll
      for (int q = 0; q < 4; ++q) {
        const size_t idx = (size_t)(row0 + mf * 16 + gq * 4 + q) * 128 + col;
        unsafeAtomicAdd(&node_part[idx], nv[q]);
        unsafeAtomicAdd(&edge_part[idx], ev[q]);
      }
    }
  }
}

// ---------------------------------------------------------------------------
// Kernel 3: out = relu(node_part + node_bias) + edge_part + edge_bias
// ---------------------------------------------------------------------------
__global__ __launch_bounds__(256) void fgc_final(
    const float* __restrict__ node_part, const float* __restrict__ edge_part,
    const float* __restrict__ node_bias, const float* __restrict__ edge_bias,
    float* __restrict__ out) {
  const int idx = blockIdx.x * 256 + threadIdx.x;  // one float4 each
  const int col = (idx * 4) & 127;
  const float4 n = ((const float4*)node_part)[idx];
  const float4 e = ((const float4*)edge_part)[idx];
  const float4 nb = *(const float4*)(node_bias + col);
  const float4 eb = *(const float4*)(edge_bias + col);
  float4 o;
  o.x = fmaxf(n.x + nb.x, 0.f) + e.x + eb.x;
  o.y = fmaxf(n.y + nb.y, 0.f) + e.y + eb.y;
  o.z = fmaxf(n.z + nb.z, 0.f) + e.z + eb.z;
  o.w = fmaxf(n.w + nb.w, 0.f) + e.w + eb.w;
  ((float4*)out)[idx] = o;
}

extern "C" void kernel_launch(void* const* d_in, const int* in_sizes, int n_in,
                              void* d_out, int out_size, void* d_ws, size_t ws_size,
                              hipStream_t stream) {
  const float* feats = (const float*)d_in[0];
  const float* node_adj = (const float*)d_in[1];
  const float* edge_adj = (const float*)d_in[2];
  const float* node_w = (const float*)d_in[3];
  const float* node_b = (const float*)d_in[4];
  const float* edge_w = (const float*)d_in[5];
  const float* edge_b = (const float*)d_in[6];
  uint16_t* gt = (uint16_t*)d_ws;                 // 9.44 MB
  float* node_part = (float*)d_ws + NPART_OFF;    // 6.29 MB
  float* edge_part = (float*)d_ws + EPART_OFF;    // 6.29 MB

  gw_kernel<<<768, 256, 0, stream>>>(feats, node_w, edge_w, gt);
  hipMemsetAsync((char*)d_ws + 9437184, 0, 2 * 6291456, stream);
  fgc_main<<<1536, 64, 0, stream>>>(node_adj, edge_adj, gt,
                                    node_part, edge_part);
  fgc_final<<<1536, 256, 0, stream>>>(node_part, edge_part, node_b, edge_b,
                                      (float*)d_out);
}

// Round 5
// 561.012 us; speedup vs baseline: 1.2534x; 1.2534x over previous
//
#include <hip/hip_runtime.h>
#include <stdint.h>

#define N_ROWS 12288
#define GSZ (128 * 12288)  // elements per G matrix (bf16)
#define NPART_OFF (9437184 / 4)          // float offset of node partials in ws
#define EPART_OFF ((9437184 + 6291456) / 4)

typedef __attribute__((ext_vector_type(8))) short bf16x8;
typedef __attribute__((ext_vector_type(4))) float f32x4;
typedef __attribute__((ext_vector_type(4))) float f32x4v;

__device__ __forceinline__ uint32_t f2bf(float x) {
  union { float f; uint32_t u; } c; c.f = x;
  return (c.u + 0x7FFFu + ((c.u >> 16) & 1u)) >> 16;
}
__device__ __forceinline__ uint32_t pk_bf(float a, float b) {
  return f2bf(a) | (f2bf(b) << 16);
}
__device__ __forceinline__ uint32_t pk_pos(float a, float b) {
  return (a > 0.f ? 0x3F80u : 0u) | (b > 0.f ? 0x3F800000u : 0u);
}
__device__ __forceinline__ uint32_t pk_neg(float a, float b) {
  return (a < 0.f ? 0x3F80u : 0u) | (b < 0.f ? 0x3F800000u : 0u);
}

// ---------------------------------------------------------------------------
// Kernel 1: G_j = feats @ W_j  (fp32), stored bf16 TRANSPOSED:
//   gt[j][n][k] = (feats @ W_j)[k][n]
// ---------------------------------------------------------------------------
__global__ __launch_bounds__(256) void gw_kernel(
    const float* __restrict__ feats, const float* __restrict__ node_w,
    const float* __restrict__ edge_w, uint16_t* __restrict__ gt) {
  __shared__ float lf[16 * 128];
  const int t = threadIdx.x;
  const int kb = blockIdx.x * 16;
  {
    const float4* src = (const float4*)(feats + (size_t)kb * 128);
    float4* dst = (float4*)lf;
    dst[t] = src[t];
    dst[t + 256] = src[t + 256];
  }
  __syncthreads();
  const int n = t & 127;
  const int rh = t >> 7;
  const float* wb[3] = {node_w, node_w + 128 * 128, edge_w};
#pragma unroll
  for (int j = 0; j < 3; ++j) {
    const float* W = wb[j] + n;
    float acc[8];
#pragma unroll
    for (int q = 0; q < 8; ++q) acc[q] = 0.f;
    for (int i = 0; i < 128; i += 4) {
      const float w0 = W[(i + 0) * 128];
      const float w1 = W[(i + 1) * 128];
      const float w2 = W[(i + 2) * 128];
      const float w3 = W[(i + 3) * 128];
#pragma unroll
      for (int q = 0; q < 8; ++q) {
        const float4 f = *(const float4*)&lf[(rh * 8 + q) * 128 + i];
        acc[q] = fmaf(f.w, w3, fmaf(f.z, w2, fmaf(f.y, w1, fmaf(f.x, w0, acc[q]))));
      }
    }
    uint4 o;
    o.x = pk_bf(acc[0], acc[1]);
    o.y = pk_bf(acc[2], acc[3]);
    o.z = pk_bf(acc[4], acc[5]);
    o.w = pk_bf(acc[6], acc[7]);
    *(uint4*)(gt + (size_t)j * GSZ + (size_t)n * N_ROWS + kb + rh * 8) = o;
  }
}

// ---------------------------------------------------------------------------
// Kernel 2: K-sliced partials. 768 blocks x 256 thr (4 waves).
// BM=64, BK=64, slice=3072 (48 iters). XCD-affinity: slice=(bid>>1)&3.
// ISSUE ORDER per iter (vmcnt is in-order!):
//   [B-loads kt]  [pack+ds_write kt]  [adj loads kt+1]  [lgkmcnt(0); raw
//   s_barrier -- adj+B stay in flight]  [ds_read A + MFMA using B regs]
// B consumers never wait on adjacency (adj younger); adjacency gets one
// full MFMA phase of cover; HBM never drains at the barrier.
// ---------------------------------------------------------------------------
__global__ __launch_bounds__(256) void fgc_main(
    const float* __restrict__ node_adj, const float* __restrict__ edge_adj,
    const uint16_t* __restrict__ gt, float* __restrict__ node_part,
    float* __restrict__ edge_part) {
  __shared__ __align__(128) char smem[49152];  // 2 x (pos|neg|edge) x 64x64 bf16
  const int t = threadIdx.x;
  const int l = t & 63;
  const int w = t >> 6;
  const int bid = blockIdx.x;
  const int slice = (bid >> 1) & 3;
  const int rowt = ((bid >> 3) << 1) | (bid & 1);
  const int row0 = rowt * 64;
  const size_t k0 = (size_t)slice * 3072;

  // staging: thread t owns (row t>>2, k-quarter t&3) = 16 consecutive f32
  const int r = t >> 2, q4 = t & 3;
  const float* np_ = node_adj + (size_t)(row0 + r) * N_ROWS + k0 + q4 * 16;
  const float* ep_ = edge_adj + (size_t)(row0 + r) * N_ROWS + k0 + q4 * 16;
  const int g0 = q4 * 2, g1 = q4 * 2 + 1;
  const int wOffA = r * 128 + ((g0 ^ (r & 7)) * 16);  // swizzled LDS byte offs
  const int wOffB = r * 128 + ((g1 ^ (r & 7)) * 16);

  // A-frag read: row = mf*16 + (l&15), col-granule = ks*4 + (l>>4)
  const int arow = (l & 15) * 128;
  const int rx = l & 7;
  const int gq = l >> 4;

  // B lane base: n = w*32 + nf*16 + (l&15), k = k0 + kt*64 + ks*32 + gq*8
  const uint16_t* gB = gt + (size_t)(w * 32 + (l & 15)) * N_ROWS + k0 + gq * 8;

  f32x4 accn[4][2], acce[4][2];
#pragma unroll
  for (int a = 0; a < 4; ++a)
#pragma unroll
    for (int b = 0; b < 2; ++b) {
      accn[a][b] = {0.f, 0.f, 0.f, 0.f};
      acce[a][b] = {0.f, 0.f, 0.f, 0.f};
    }

  // prologue: issue adjacency for kt=0 (non-temporal: don't evict gt from L2)
  f32x4v rn0, rn1, rn2, rn3, re0, re1, re2, re3;
  rn0 = __builtin_nontemporal_load((const f32x4v*)(np_));
  rn1 = __builtin_nontemporal_load((const f32x4v*)(np_ + 4));
  rn2 = __builtin_nontemporal_load((const f32x4v*)(np_ + 8));
  rn3 = __builtin_nontemporal_load((const f32x4v*)(np_ + 12));
  re0 = __builtin_nontemporal_load((const f32x4v*)(ep_));
  re1 = __builtin_nontemporal_load((const f32x4v*)(ep_ + 4));
  re2 = __builtin_nontemporal_load((const f32x4v*)(ep_ + 8));
  re3 = __builtin_nontemporal_load((const f32x4v*)(ep_ + 12));

  for (int kt = 0; kt < 48; ++kt) {
    // ---- 1. issue ALL B loads for this iteration (oldest after adj(kt)) ----
    bf16x8 Bv[2][2][3];
    {
      const uint16_t* gk = gB + kt * 64;
#pragma unroll
      for (int ks = 0; ks < 2; ++ks)
#pragma unroll
        for (int nf = 0; nf < 2; ++nf) {
          const uint16_t* gp = gk + ks * 32 + (size_t)nf * 16 * N_ROWS;
          Bv[ks][nf][0] = *(const bf16x8*)(gp);
          Bv[ks][nf][1] = *(const bf16x8*)(gp + GSZ);
          Bv[ks][nf][2] = *(const bf16x8*)(gp + 2 * GSZ);
        }
    }
    __builtin_amdgcn_sched_barrier(0);  // pin: nothing hoists above B issues

    // ---- 2. pack adjacency kt (waits only adj(kt); B stays in flight) ----
    char* wb2 = smem + (kt & 1) * 24576;
    {
      uint4 P;
      P.x = pk_pos(rn0.x, rn0.y); P.y = pk_pos(rn0.z, rn0.w);
      P.z = pk_pos(rn1.x, rn1.y); P.w = pk_pos(rn1.z, rn1.w);
      *(uint4*)(wb2 + wOffA) = P;
      P.x = pk_pos(rn2.x, rn2.y); P.y = pk_pos(rn2.z, rn2.w);
      P.z = pk_pos(rn3.x, rn3.y); P.w = pk_pos(rn3.z, rn3.w);
      *(uint4*)(wb2 + wOffB) = P;
      P.x = pk_neg(rn0.x, rn0.y); P.y = pk_neg(rn0.z, rn0.w);
      P.z = pk_neg(rn1.x, rn1.y); P.w = pk_neg(rn1.z, rn1.w);
      *(uint4*)(wb2 + 8192 + wOffA) = P;
      P.x = pk_neg(rn2.x, rn2.y); P.y = pk_neg(rn2.z, rn2.w);
      P.z = pk_neg(rn3.x, rn3.y); P.w = pk_neg(rn3.z, rn3.w);
      *(uint4*)(wb2 + 8192 + wOffB) = P;
      P.x = pk_bf(re0.x, re0.y);  P.y = pk_bf(re0.z, re0.w);
      P.z = pk_bf(re1.x, re1.y);  P.w = pk_bf(re1.z, re1.w);
      *(uint4*)(wb2 + 16384 + wOffA) = P;
      P.x = pk_bf(re2.x, re2.y);  P.y = pk_bf(re2.z, re2.w);
      P.z = pk_bf(re3.x, re3.y);  P.w = pk_bf(re3.z, re3.w);
      *(uint4*)(wb2 + 16384 + wOffB) = P;
    }

    // ---- 3. issue adjacency kt+1 (YOUNGER than B(kt): never blocks B) ----
    if (kt < 47) {
      const size_t ko = (size_t)(kt + 1) * 64;
      rn0 = __builtin_nontemporal_load((const f32x4v*)(np_ + ko));
      rn1 = __builtin_nontemporal_load((const f32x4v*)(np_ + ko + 4));
      rn2 = __builtin_nontemporal_load((const f32x4v*)(np_ + ko + 8));
      rn3 = __builtin_nontemporal_load((const f32x4v*)(np_ + ko + 12));
      re0 = __builtin_nontemporal_load((const f32x4v*)(ep_ + ko));
      re1 = __builtin_nontemporal_load((const f32x4v*)(ep_ + ko + 4));
      re2 = __builtin_nontemporal_load((const f32x4v*)(ep_ + ko + 8));
      re3 = __builtin_nontemporal_load((const f32x4v*)(ep_ + ko + 12));
    }

    // ---- 4. LDS-write fence + RAW barrier (no vmcnt drain!) ----
    asm volatile("s_waitcnt lgkmcnt(0)" ::: "memory");
    __builtin_amdgcn_sched_barrier(0);
    __builtin_amdgcn_s_barrier();

    // ---- 5. MFMA phase: ds_read A-frags, MFMA with preloaded B regs ----
    const char* rb = smem + (kt & 1) * 24576;
#pragma unroll
    for (int ks = 0; ks < 2; ++ks) {
      const int a0 = arow + (((ks * 4 + gq) ^ rx) * 16);
      bf16x8 ap[4], an[4], ae[4];
#pragma unroll
      for (int mf = 0; mf < 4; ++mf) {
        ap[mf] = *(const bf16x8*)(rb + a0 + mf * 2048);
        an[mf] = *(const bf16x8*)(rb + 8192 + a0 + mf * 2048);
        ae[mf] = *(const bf16x8*)(rb + 16384 + a0 + mf * 2048);
      }
#pragma unroll
      for (int nf = 0; nf < 2; ++nf) {
#pragma unroll
        for (int mf = 0; mf < 4; ++mf)
          accn[mf][nf] = __builtin_amdgcn_mfma_f32_16x16x32_bf16(ap[mf], Bv[ks][nf][0], accn[mf][nf], 0, 0, 0);
#pragma unroll
        for (int mf = 0; mf < 4; ++mf)
          accn[mf][nf] = __builtin_amdgcn_mfma_f32_16x16x32_bf16(an[mf], Bv[ks][nf][1], accn[mf][nf], 0, 0, 0);
#pragma unroll
        for (int mf = 0; mf < 4; ++mf)
          acce[mf][nf] = __builtin_amdgcn_mfma_f32_16x16x32_bf16(ae[mf], Bv[ks][nf][2], acce[mf][nf], 0, 0, 0);
      }
    }
  }

  // accumulate partials: C/D frag row=(lane>>4)*4+q, col=lane&15
#pragma unroll
  for (int nf = 0; nf < 2; ++nf) {
    const int col = w * 32 + nf * 16 + (l & 15);
#pragma unroll
    for (int mf = 0; mf < 4; ++mf) {
      const f32x4 nv = accn[mf][nf];
      const f32x4 ev = acce[mf][nf];
#pragma unroll
      for (int q = 0; q < 4; ++q) {
        const size_t idx = (size_t)(row0 + mf * 16 + gq * 4 + q) * 128 + col;
        unsafeAtomicAdd(&node_part[idx], nv[q]);
        unsafeAtomicAdd(&edge_part[idx], ev[q]);
      }
    }
  }
}

// ---------------------------------------------------------------------------
// Kernel 3: out = relu(node_part + node_bias) + edge_part + edge_bias
// ---------------------------------------------------------------------------
__global__ __launch_bounds__(256) void fgc_final(
    const float* __restrict__ node_part, const float* __restrict__ edge_part,
    const float* __restrict__ node_bias, const float* __restrict__ edge_bias,
    float* __restrict__ out) {
  const int idx = blockIdx.x * 256 + threadIdx.x;  // one float4 each
  const int col = (idx * 4) & 127;
  const float4 n = ((const float4*)node_part)[idx];
  const float4 e = ((const float4*)edge_part)[idx];
  const float4 nb = *(const float4*)(node_bias + col);
  const float4 eb = *(const float4*)(edge_bias + col);
  float4 o;
  o.x = fmaxf(n.x + nb.x, 0.f) + e.x + eb.x;
  o.y = fmaxf(n.y + nb.y, 0.f) + e.y + eb.y;
  o.z = fmaxf(n.z + nb.z, 0.f) + e.z + eb.z;
  o.w = fmaxf(n.w + nb.w, 0.f) + e.w + eb.w;
  ((float4*)out)[idx] = o;
}

extern "C" void kernel_launch(void* const* d_in, const int* in_sizes, int n_in,
                              void* d_out, int out_size, void* d_ws, size_t ws_size,
                              hipStream_t stream) {
  const float* feats = (const float*)d_in[0];
  const float* node_adj = (const float*)d_in[1];
  const float* edge_adj = (const float*)d_in[2];
  const float* node_w = (const float*)d_in[3];
  const float* node_b = (const float*)d_in[4];
  const float* edge_w = (const float*)d_in[5];
  const float* edge_b = (const float*)d_in[6];
  uint16_t* gt = (uint16_t*)d_ws;                 // 9.44 MB
  float* node_part = (float*)d_ws + NPART_OFF;    // 6.29 MB
  float* edge_part = (float*)d_ws + EPART_OFF;    // 6.29 MB

  gw_kernel<<<768, 256, 0, stream>>>(feats, node_w, edge_w, gt);
  hipMemsetAsync((char*)d_ws + 9437184, 0, 2 * 6291456, stream);
  fgc_main<<<768, 256, 0, stream>>>(node_adj, edge_adj, gt,
                                    node_part, edge_part);
  fgc_final<<<1536, 256, 0, stream>>>(node_part, edge_part, node_b, edge_b,
                                      (float*)d_out);
}

// Round 6
// 418.161 us; speedup vs baseline: 1.6816x; 1.3416x over previous
//
#include <hip/hip_runtime.h>
#include <stdint.h>

#define N_ROWS 12288
#define GSZ (128 * 12288)  // elements per G matrix (bf16)
#define NPART_OFF (9437184 / 4)          // float offset of node partials in ws
#define EPART_OFF ((9437184 + 6291456) / 4)

typedef __attribute__((ext_vector_type(8))) short bf16x8;
typedef __attribute__((ext_vector_type(4))) float f32x4;

__device__ __forceinline__ uint32_t f2bf(float x) {
  union { float f; uint32_t u; } c; c.f = x;
  return (c.u + 0x7FFFu + ((c.u >> 16) & 1u)) >> 16;
}
__device__ __forceinline__ uint32_t pk_bf(float a, float b) {
  return f2bf(a) | (f2bf(b) << 16);
}
__device__ __forceinline__ uint32_t pk_pos(float a, float b) {
  return (a > 0.f ? 0x3F80u : 0u) | (b > 0.f ? 0x3F800000u : 0u);
}
__device__ __forceinline__ uint32_t pk_neg(float a, float b) {
  return (a < 0.f ? 0x3F80u : 0u) | (b < 0.f ? 0x3F800000u : 0u);
}

// ---------------------------------------------------------------------------
// Kernel 1: G_j = feats @ W_j  (fp32), stored bf16 TRANSPOSED:
//   gt[j][n][k] = (feats @ W_j)[k][n]
// ---------------------------------------------------------------------------
__global__ __launch_bounds__(256) void gw_kernel(
    const float* __restrict__ feats, const float* __restrict__ node_w,
    const float* __restrict__ edge_w, uint16_t* __restrict__ gt) {
  __shared__ float lf[16 * 128];
  const int t = threadIdx.x;
  const int kb = blockIdx.x * 16;
  {
    const float4* src = (const float4*)(feats + (size_t)kb * 128);
    float4* dst = (float4*)lf;
    dst[t] = src[t];
    dst[t + 256] = src[t + 256];
  }
  __syncthreads();
  const int n = t & 127;
  const int rh = t >> 7;
  const float* wb[3] = {node_w, node_w + 128 * 128, edge_w};
#pragma unroll
  for (int j = 0; j < 3; ++j) {
    const float* W = wb[j] + n;
    float acc[8];
#pragma unroll
    for (int q = 0; q < 8; ++q) acc[q] = 0.f;
    for (int i = 0; i < 128; i += 4) {
      const float w0 = W[(i + 0) * 128];
      const float w1 = W[(i + 1) * 128];
      const float w2 = W[(i + 2) * 128];
      const float w3 = W[(i + 3) * 128];
#pragma unroll
      for (int q = 0; q < 8; ++q) {
        const float4 f = *(const float4*)&lf[(rh * 8 + q) * 128 + i];
        acc[q] = fmaf(f.w, w3, fmaf(f.z, w2, fmaf(f.y, w1, fmaf(f.x, w0, acc[q]))));
      }
    }
    uint4 o;
    o.x = pk_bf(acc[0], acc[1]);
    o.y = pk_bf(acc[2], acc[3]);
    o.z = pk_bf(acc[4], acc[5]);
    o.w = pk_bf(acc[6], acc[7]);
    *(uint4*)(gt + (size_t)j * GSZ + (size_t)n * N_ROWS + kb + rh * 8) = o;
  }
}

// ---------------------------------------------------------------------------
// Kernel 2: K-sliced partials. 1536 blocks x 256 thr (4 waves), 4 blocks/CU
// (LDS 24KB, VGPR<=128). BM=64, BK=32, 8 K-slices of 1536 (48 iters).
// XCD-affinity: slice = bid&7 = XCD id -> per-XCD gt working set 1.18MB.
// Same per-iter structure as the R3 best: pack+ds_write, __syncthreads,
// prefetch kt+1, B-loads+MFMA (compiler-scheduled).
// LDS tile: 3 mats x 64 rows x 32 bf16 (64B rows); granule swizzle
// g ^= (row>>2)&3 -> even 2-lanes/bank-quad on write and read.
// ---------------------------------------------------------------------------
__global__ __launch_bounds__(256, 4) void fgc_main(
    const float* __restrict__ node_adj, const float* __restrict__ edge_adj,
    const uint16_t* __restrict__ gt, float* __restrict__ node_part,
    float* __restrict__ edge_part) {
  __shared__ __align__(128) char smem[24576];  // 2 x (pos|neg|edge) x 64x32 bf16
  const int t = threadIdx.x;
  const int l = t & 63;
  const int w = t >> 6;
  const int bid = blockIdx.x;
  const int slice = bid & 7;
  const int row0 = (bid >> 3) * 64;
  const size_t k0 = (size_t)slice * 1536;

  // staging: thread t owns (row t>>2, granule t&3) = 8 consecutive f32
  const int r = t >> 2, o = t & 3;
  const float* np_ = node_adj + (size_t)(row0 + r) * N_ROWS + k0 + o * 8;
  const float* ep_ = edge_adj + (size_t)(row0 + r) * N_ROWS + k0 + o * 8;
  const int wOff = r * 64 + ((o ^ ((r >> 2) & 3)) * 16);  // swizzled byte offs

  // A-frag read: row = mf*16 + r15, granule gq, swizzle by (row>>2)&3
  const int r15 = l & 15;
  const int gq = l >> 4;
  const int abase = r15 * 64 + ((gq ^ ((r15 >> 2) & 3)) * 16);

  // B lane base: n = w*32 + nf*16 + r15, k = k0 + kt*32 + gq*8
  const uint16_t* gB = gt + (size_t)(w * 32 + r15) * N_ROWS + k0 + gq * 8;

  f32x4 accn[4][2], acce[4][2];
#pragma unroll
  for (int a = 0; a < 4; ++a)
#pragma unroll
    for (int b = 0; b < 2; ++b) {
      accn[a][b] = {0.f, 0.f, 0.f, 0.f};
      acce[a][b] = {0.f, 0.f, 0.f, 0.f};
    }

  float4 rn0, rn1, re0, re1;
  rn0 = *(const float4*)(np_);
  rn1 = *(const float4*)(np_ + 4);
  re0 = *(const float4*)(ep_);
  re1 = *(const float4*)(ep_ + 4);

  for (int kt = 0; kt < 48; ++kt) {
    char* wb2 = smem + (kt & 1) * 12288;
    {
      uint4 P, Q, E;
      P.x = pk_pos(rn0.x, rn0.y); P.y = pk_pos(rn0.z, rn0.w);
      P.z = pk_pos(rn1.x, rn1.y); P.w = pk_pos(rn1.z, rn1.w);
      Q.x = pk_neg(rn0.x, rn0.y); Q.y = pk_neg(rn0.z, rn0.w);
      Q.z = pk_neg(rn1.x, rn1.y); Q.w = pk_neg(rn1.z, rn1.w);
      E.x = pk_bf(re0.x, re0.y);  E.y = pk_bf(re0.z, re0.w);
      E.z = pk_bf(re1.x, re1.y);  E.w = pk_bf(re1.z, re1.w);
      *(uint4*)(wb2 + wOff) = P;
      *(uint4*)(wb2 + 4096 + wOff) = Q;
      *(uint4*)(wb2 + 8192 + wOff) = E;
    }
    __syncthreads();
    // prefetch next tile AFTER the barrier: the barrier's vmcnt drain then
    // only covers already-consumed loads.
    if (kt < 47) {
      const size_t ko = (size_t)(kt + 1) * 32;
      rn0 = *(const float4*)(np_ + ko);
      rn1 = *(const float4*)(np_ + ko + 4);
      re0 = *(const float4*)(ep_ + ko);
      re1 = *(const float4*)(ep_ + ko + 4);
    }
    const char* rb = smem + (kt & 1) * 12288;
    bf16x8 ap[4], an[4], ae[4];
#pragma unroll
    for (int mf = 0; mf < 4; ++mf) {
      ap[mf] = *(const bf16x8*)(rb + abase + mf * 1024);
      an[mf] = *(const bf16x8*)(rb + 4096 + abase + mf * 1024);
      ae[mf] = *(const bf16x8*)(rb + 8192 + abase + mf * 1024);
    }
    const uint16_t* gk = gB + kt * 32;
#pragma unroll
    for (int nf = 0; nf < 2; ++nf) {
      const uint16_t* gp = gk + (size_t)nf * 16 * N_ROWS;
      const bf16x8 b1 = *(const bf16x8*)(gp);
      const bf16x8 b2 = *(const bf16x8*)(gp + GSZ);
      const bf16x8 b3 = *(const bf16x8*)(gp + 2 * GSZ);
#pragma unroll
      for (int mf = 0; mf < 4; ++mf)
        accn[mf][nf] = __builtin_amdgcn_mfma_f32_16x16x32_bf16(ap[mf], b1, accn[mf][nf], 0, 0, 0);
#pragma unroll
      for (int mf = 0; mf < 4; ++mf)
        accn[mf][nf] = __builtin_amdgcn_mfma_f32_16x16x32_bf16(an[mf], b2, accn[mf][nf], 0, 0, 0);
#pragma unroll
      for (int mf = 0; mf < 4; ++mf)
        acce[mf][nf] = __builtin_amdgcn_mfma_f32_16x16x32_bf16(ae[mf], b3, acce[mf][nf], 0, 0, 0);
    }
  }

  // accumulate partials: C/D frag row=(lane>>4)*4+q, col=lane&15
#pragma unroll
  for (int nf = 0; nf < 2; ++nf) {
    const int col = w * 32 + nf * 16 + r15;
#pragma unroll
    for (int mf = 0; mf < 4; ++mf) {
      const f32x4 nv = accn[mf][nf];
      const f32x4 ev = acce[mf][nf];
#pragma unroll
      for (int q = 0; q < 4; ++q) {
        const size_t idx = (size_t)(row0 + mf * 16 + gq * 4 + q) * 128 + col;
        unsafeAtomicAdd(&node_part[idx], nv[q]);
        unsafeAtomicAdd(&edge_part[idx], ev[q]);
      }
    }
  }
}

// ---------------------------------------------------------------------------
// Kernel 3: out = relu(node_part + node_bias) + edge_part + edge_bias
// ---------------------------------------------------------------------------
__global__ __launch_bounds__(256) void fgc_final(
    const float* __restrict__ node_part, const float* __restrict__ edge_part,
    const float* __restrict__ node_bias, const float* __restrict__ edge_bias,
    float* __restrict__ out) {
  const int idx = blockIdx.x * 256 + threadIdx.x;  // one float4 each
  const int col = (idx * 4) & 127;
  const float4 n = ((const float4*)node_part)[idx];
  const float4 e = ((const float4*)edge_part)[idx];
  const float4 nb = *(const float4*)(node_bias + col);
  const float4 eb = *(const float4*)(edge_bias + col);
  float4 o;
  o.x = fmaxf(n.x + nb.x, 0.f) + e.x + eb.x;
  o.y = fmaxf(n.y + nb.y, 0.f) + e.y + eb.y;
  o.z = fmaxf(n.z + nb.z, 0.f) + e.z + eb.z;
  o.w = fmaxf(n.w + nb.w, 0.f) + e.w + eb.w;
  ((float4*)out)[idx] = o;
}

extern "C" void kernel_launch(void* const* d_in, const int* in_sizes, int n_in,
                              void* d_out, int out_size, void* d_ws, size_t ws_size,
                              hipStream_t stream) {
  const float* feats = (const float*)d_in[0];
  const float* node_adj = (const float*)d_in[1];
  const float* edge_adj = (const float*)d_in[2];
  const float* node_w = (const float*)d_in[3];
  const float* node_b = (const float*)d_in[4];
  const float* edge_w = (const float*)d_in[5];
  const float* edge_b = (const float*)d_in[6];
  uint16_t* gt = (uint16_t*)d_ws;                 // 9.44 MB
  float* node_part = (float*)d_ws + NPART_OFF;    // 6.29 MB
  float* edge_part = (float*)d_ws + EPART_OFF;    // 6.29 MB

  gw_kernel<<<768, 256, 0, stream>>>(feats, node_w, edge_w, gt);
  hipMemsetAsync((char*)d_ws + 9437184, 0, 2 * 6291456, stream);
  fgc_main<<<1536, 256, 0, stream>>>(node_adj, edge_adj, gt,
                                     node_part, edge_part);
  fgc_final<<<1536, 256, 0, stream>>>(node_part, edge_part, node_b, edge_b,
                                      (float*)d_out);
}